// Round 15
// baseline (187.125 us; speedup 1.0000x reference)
//
#include <hip/hip_runtime.h>
#include <hip/hip_bf16.h>
#include <hip/hip_fp16.h>

using half8  = __attribute__((ext_vector_type(8))) _Float16;
using float4v = __attribute__((ext_vector_type(4))) float;
using f32x16 = __attribute__((ext_vector_type(16))) float;
typedef unsigned int uint;

#define A_DIM 4
#define M_DIM 2048
#define E_DIM 1024
#define H_DIM 16
#define C_DIM 64
#define PLANE (M_DIM * C_DIM)              // 131072 elements per (a,h)
#define PROJ_ELEMS (A_DIM * H_DIM * PLANE) // 8388608
#define LOG2E 1.44269504088896f

#define GLOAD_LDS16(g, l) __builtin_amdgcn_global_load_lds( \
    (const __attribute__((address_space(1))) void*)(g), \
    (__attribute__((address_space(3))) void*)(l), 16, 0, 0)

#if __has_builtin(__builtin_amdgcn_exp2f)
#define EXP2F(x) __builtin_amdgcn_exp2f(x)
#else
#define EXP2F(x) exp2f(x)
#endif

// f32 pair -> packed fp16 (RTZ) as uint bits
static __device__ __forceinline__ uint pk16(float a, float b) {
    auto r = __builtin_amdgcn_cvt_pkrtz(a, b);   // __fp16 x2
    return __builtin_bit_cast(uint, r);
}

// read 8 logical-contiguous f32 from a swizzled f32 LDS tile (256B rows,
// 16B blocks XOR'd by (row&7)<<4), convert to half8 via cvt_pkrtz. [R6-exact]
static __device__ __forceinline__ half8 ldsfrag_cvt256(const float* base, int row, int colbyte) {
    const char* b = (const char*)base;
    int off = row * 256 + (colbyte ^ ((row & 7) << 4));
    float4v x0 = *reinterpret_cast<const float4v*>(b + off);
    float4v x1 = *reinterpret_cast<const float4v*>(b + (off ^ 16));
    union { uint u[4]; half8 v; } r;
    r.u[0] = pk16(x0[0], x0[1]);
    r.u[1] = pk16(x0[2], x0[3]);
    r.u[2] = pk16(x1[0], x1[1]);
    r.u[3] = pk16(x1[2], x1[3]);
    return r.v;
}

// ---------------------------------------------------------------------------
// W f32 -> fp16 prepass (FROZEN from R12).
// ---------------------------------------------------------------------------
__global__ __launch_bounds__(256)
void wcvt_kernel(const float* __restrict__ Wq, const float* __restrict__ Wk,
                 const float* __restrict__ Wv, _Float16* __restrict__ wh)
{
    const float* W = (blockIdx.y == 0) ? Wq : (blockIdx.y == 1) ? Wk : Wv;
    _Float16* o = wh + (size_t)blockIdx.y * E_DIM * E_DIM;
    int i = (blockIdx.x * 256 + threadIdx.x) * 8;
    float4v x0 = *reinterpret_cast<const float4v*>(&W[i]);
    float4v x1 = *reinterpret_cast<const float4v*>(&W[i + 4]);
    union { uint u[4]; half8 h; } r;
    r.u[0] = pk16(x0[0], x0[1]);
    r.u[1] = pk16(x0[2], x0[3]);
    r.u[2] = pk16(x1[0], x1[1]);
    r.u[3] = pk16(x1[2], x1[3]);
    *reinterpret_cast<half8*>(&o[i]) = r.h;
}

// ---------------------------------------------------------------------------
// Projection GEMM (FROZEN from R12): R6 structure, fp16 B-side. ~29us each.
// ---------------------------------------------------------------------------
template<int MODE>
__global__ __launch_bounds__(256, 3)
void proj_kernel(const float* __restrict__ X, const _Float16* __restrict__ Wh,
                 const float* __restrict__ bias, _Float16* __restrict__ out)
{
    __shared__ float    ldsA[128 * 64];   // 32 KB, 256B rows (f32)
    __shared__ _Float16 ldsB[128 * 64];   // 16 KB, 128B rows (fp16)

    const int tid  = threadIdx.x;
    const int lane = tid & 63;
    const int wave = tid >> 6;
    const int wr = wave >> 1, wc = wave & 1;
    const int g = lane >> 4, r16 = lane & 15;
    const int R0 = blockIdx.x * 128;
    const int C0 = blockIdx.y * 128;

    float4v acc[4][4];
#pragma unroll
    for (int i = 0; i < 4; i++)
#pragma unroll
        for (int j = 0; j < 4; j++) acc[i][j] = {0.f, 0.f, 0.f, 0.f};

    for (int k0 = 0; k0 < E_DIM; k0 += 64) {
        __syncthreads();
#pragma unroll
        for (int i = 0; i < 8; i++) {          // A: 2048 16B-segs, f32
            int s    = i * 256 + tid;
            int row  = s >> 4;
            int swzo = ((s & 15) * 16) ^ ((row & 7) << 4);
            const char* asrc = (const char*)&X[(size_t)(R0 + row) * E_DIM + k0] + swzo;
            GLOAD_LDS16(asrc, &ldsA[s * 4]);
        }
#pragma unroll
        for (int i = 0; i < 4; i++) {          // B: 1024 16B-segs, fp16
            int s    = i * 256 + tid;
            int row  = s >> 3;
            int swzo = ((s & 7) * 16) ^ ((row & 7) << 4);
            const char* bsrc = (const char*)&Wh[(size_t)(C0 + row) * E_DIM + k0] + swzo;
            GLOAD_LDS16(bsrc, &ldsB[s * 8]);
        }
        __syncthreads();

#pragma unroll
        for (int kc = 0; kc < 2; kc++) {
            half8 af[4], bf[4];
#pragma unroll
            for (int mi = 0; mi < 4; mi++)
                af[mi] = ldsfrag_cvt256(ldsA, wr * 64 + mi * 16 + r16, kc * 128 + g * 32);
#pragma unroll
            for (int ni = 0; ni < 4; ni++) {
                int row = wc * 64 + ni * 16 + r16;
                bf[ni] = *reinterpret_cast<const half8*>(
                    (const char*)ldsB + row * 128 + ((kc * 64 + g * 16) ^ ((row & 7) << 4)));
            }
#pragma unroll
            for (int mi = 0; mi < 4; mi++)
#pragma unroll
                for (int ni = 0; ni < 4; ni++)
                    acc[mi][ni] = __builtin_amdgcn_mfma_f32_16x16x32_f16(af[mi], bf[ni], acc[mi][ni], 0, 0, 0);
        }
    }

#pragma unroll
    for (int mi = 0; mi < 4; mi++) {
#pragma unroll
        for (int ni = 0; ni < 4; ni++) {
            const int jb = C0 + wc * 64 + ni * 16 + r16;
            const int h  = jb >> 6;
            const int cc = jb & 63;
            const float bv = bias[jb];
            if (MODE == 0) {
#pragma unroll
                for (int reg = 0; reg < 4; reg++) {
                    int b = R0 + wr * 64 + mi * 16 + g * 4 + reg;
                    float val = acc[mi][ni][reg] + bv;
                    size_t o = (size_t)((b >> 11) * H_DIM + h) * PLANE + (size_t)(b & (M_DIM - 1)) * C_DIM + cc;
                    out[o] = (_Float16)val;
                }
            } else {
                int b0 = R0 + wr * 64 + mi * 16 + g * 4;
                uint u0 = pk16(acc[mi][ni][0] + bv, acc[mi][ni][1] + bv);
                uint u1 = pk16(acc[mi][ni][2] + bv, acc[mi][ni][3] + bv);
                size_t o = (size_t)((b0 >> 11) * H_DIM + h) * PLANE + (size_t)cc * M_DIM + (b0 & (M_DIM - 1));
                *reinterpret_cast<uint*>(&out[o]) = u0;
                *reinterpret_cast<uint*>(&out[o] + 2) = u1;
            }
        }
    }
}

// ---------------------------------------------------------------------------
// Flash attention v3: R14 structure (64 q-rows/wave, shared kf/vf reads) with
// the tile loop UNROLLED x2 so the double-buffer index is COMPILE-TIME:
// all LDS addresses become loop-invariant (hoisted) and buffer selection
// folds into offset immediates. Softmax/pack numerics byte-identical to R13.
// ---------------------------------------------------------------------------
__global__ __launch_bounds__(256, 2)
void flash_kernel(const _Float16* __restrict__ qp, const _Float16* __restrict__ kp,
                  const _Float16* __restrict__ vt, float* __restrict__ out)
{
    __shared__ _Float16 smem[2][2][4096];   // [dbuf][K|V][64 rows x 64 cols]

    const int tid  = threadIdx.x;
    const int lane = tid & 63;
    const int wave = tid >> 6;
    const int l31  = lane & 31;
    const int hi   = lane >> 5;

    // 512 wgs, 8 XCDs -> each XCD owns 8 whole planes (K/V fit its L2)
    const int bid = blockIdx.x;
    const int wg  = ((bid & 7) << 6) | (bid >> 3);
    const int plane_i = wg >> 3;          // 0..63
    const int qt      = wg & 7;           // 0..7 : 256-q-row block
    const size_t plane = (size_t)plane_i * PLANE;
    const int q0 = qt * 256 + wave * 64;  // wave's two halves: q0, q0+32

    const int srow  = tid >> 3;
    const int lincb = (tid & 7) * 16;
    const int scb   = lincb ^ ((srow & 7) << 4);

    half8 qf0[4], qf1[4];
#pragma unroll
    for (int ch = 0; ch < 4; ch++) {
        qf0[ch] = *reinterpret_cast<const half8*>(&qp[plane + (size_t)(q0 + l31) * C_DIM + ch * 16 + hi * 8]);
        qf1[ch] = *reinterpret_cast<const half8*>(&qp[plane + (size_t)(q0 + 32 + l31) * C_DIM + ch * 16 + hi * 8]);
    }

    f32x16 o00, o01, o10, o11;            // [qh][db]
#pragma unroll
    for (int i = 0; i < 16; i++) { o00[i] = 0.f; o01[i] = 0.f; o10[i] = 0.f; o11[i] = 0.f; }
    float m0 = 0.f, mK0 = 0.f, l0 = 0.f;
    float m1 = 0.f, mK1 = 0.f, l1 = 0.f;

    auto stage = [&](int buf, int t0) {
#pragma unroll
        for (int i = 0; i < 2; i++) {
            int row = srow + 32 * i;
            const char* ksrc = (const char*)&kp[plane + (size_t)(t0 + row) * C_DIM] + scb;
            const char* vsrc = (const char*)&vt[plane + (size_t)row * M_DIM + t0] + scb;
            GLOAD_LDS16(ksrc, &smem[buf][0][tid * 8 + 2048 * i]);
            GLOAD_LDS16(vsrc, &smem[buf][1][tid * 8 + 2048 * i]);
        }
    };

    // per-tile body; BUF is a compile-time constant at every call site, so
    // kbase/vbase and all derived ds_read addresses are loop-invariant.
    auto tile = [&](const _Float16* kb, const _Float16* vb) {
        const char* kbase = (const char*)kb;
        const char* vbase = (const char*)vb;
#pragma unroll
        for (int st = 0; st < 2; ++st) {
            const int krow = st * 32 + l31;
            const int kswz = (krow & 7) << 4;

            half8 kf[4];
#pragma unroll
            for (int ch = 0; ch < 4; ch++)
                kf[ch] = *reinterpret_cast<const half8*>(kbase + krow * 128 + ((ch * 32 + hi * 16) ^ kswz));

            f32x16 s0, s1;
#pragma unroll
            for (int i = 0; i < 16; i++) { s0[i] = 0.f; s1[i] = 0.f; }
            __builtin_amdgcn_s_setprio(1);
#pragma unroll
            for (int ch = 0; ch < 4; ch++) {
                s0 = __builtin_amdgcn_mfma_f32_32x32x16_f16(kf[ch], qf0[ch], s0, 0, 0, 0);
                s1 = __builtin_amdgcn_mfma_f32_32x32x16_f16(kf[ch], qf1[ch], s1, 0, 0, 0);
            }
            __builtin_amdgcn_s_setprio(0);

            half8 pf0[2], pf1[2];
#pragma unroll
            for (int qh = 0; qh < 2; qh++) {
                f32x16& s = qh ? s1 : s0;
                float& m = qh ? m1 : m0;
                float& mK = qh ? mK1 : mK0;
                float& l = qh ? l1 : l0;
                half8* pf = qh ? pf1 : pf0;
                f32x16& oa = qh ? o10 : o00;
                f32x16& ob = qh ? o11 : o01;

                float p[16];
#pragma unroll
                for (int r = 0; r < 16; r++) p[r] = EXP2F(fmaf(s[r], LOG2E, -mK));

                float a0 = fmaxf(fmaxf(s[0],  s[1]),  s[2]);
                float a1 = fmaxf(fmaxf(s[3],  s[4]),  s[5]);
                float a2 = fmaxf(fmaxf(s[6],  s[7]),  s[8]);
                float a3 = fmaxf(fmaxf(s[9],  s[10]), s[11]);
                float a4 = fmaxf(fmaxf(s[12], s[13]), s[14]);
                float pm = fmaxf(fmaxf(fmaxf(a0, a1), a2),
                                 fmaxf(fmaxf(a3, a4), s[15]));
                pm = fmaxf(pm, __shfl_xor(pm, 32));
                if (!__all(pm <= m + 8.f)) {
                    float mnew = fmaxf(m, pm);
                    float sc = EXP2F((m - mnew) * LOG2E);
                    m = mnew; mK = m * LOG2E;
                    l *= sc;
                    oa *= sc; ob *= sc;
#pragma unroll
                    for (int r = 0; r < 16; r++) p[r] *= sc;
                }
                float t0a = (p[0] + p[1]) + (p[2] + p[3]);
                float t1a = (p[4] + p[5]) + (p[6] + p[7]);
                float t2a = (p[8] + p[9]) + (p[10] + p[11]);
                float t3a = (p[12] + p[13]) + (p[14] + p[15]);
                l += (t0a + t1a) + (t2a + t3a);

#pragma unroll
                for (int c0 = 0; c0 < 2; c0++) {
                    uint ua0 = pk16(p[8 * c0 + 0], p[8 * c0 + 1]);
                    uint ua1 = pk16(p[8 * c0 + 2], p[8 * c0 + 3]);
                    uint ub0 = pk16(p[8 * c0 + 4], p[8 * c0 + 5]);
                    uint ub1 = pk16(p[8 * c0 + 6], p[8 * c0 + 7]);
                    union { int u[4]; half8 v; } pu;
#if __has_builtin(__builtin_amdgcn_permlane32_swap)
                    auto r0 = __builtin_amdgcn_permlane32_swap((int)ua0, (int)ub0, false, false);
                    auto r1 = __builtin_amdgcn_permlane32_swap((int)ua1, (int)ub1, false, false);
                    pu.u[0] = r0[0];
                    pu.u[1] = r1[0];
                    pu.u[2] = r0[1];
                    pu.u[3] = r1[1];
#else
                    uint v0 = hi ? ua0 : ub0;
                    uint v1 = hi ? ua1 : ub1;
                    uint y0 = (uint)__shfl_xor((int)v0, 32);
                    uint y1 = (uint)__shfl_xor((int)v1, 32);
                    pu.u[0] = hi ? y0 : ua0;
                    pu.u[1] = hi ? y1 : ua1;
                    pu.u[2] = hi ? ub0 : y0;
                    pu.u[3] = hi ? ub1 : y1;
#endif
                    pf[c0] = pu.v;
                }
            }

            __builtin_amdgcn_s_setprio(1);
#pragma unroll
            for (int db = 0; db < 2; db++) {
                const int vrow = db * 32 + l31;
                const int vswz = (vrow & 7) << 4;
#pragma unroll
                for (int c0 = 0; c0 < 2; c0++) {
                    half8 vf = *reinterpret_cast<const half8*>(
                        vbase + vrow * 128 + ((st * 64 + c0 * 32 + hi * 16) ^ vswz));
                    if (db == 0) {
                        o00 = __builtin_amdgcn_mfma_f32_32x32x16_f16(vf, pf0[c0], o00, 0, 0, 0);
                        o10 = __builtin_amdgcn_mfma_f32_32x32x16_f16(vf, pf1[c0], o10, 0, 0, 0);
                    } else {
                        o01 = __builtin_amdgcn_mfma_f32_32x32x16_f16(vf, pf0[c0], o01, 0, 0, 0);
                        o11 = __builtin_amdgcn_mfma_f32_32x32x16_f16(vf, pf1[c0], o11, 0, 0, 0);
                    }
                }
            }
            __builtin_amdgcn_s_setprio(0);
        }
    };

    stage(0, 0);

    // tile loop unrolled x2: buffer index is a literal at each call site
#pragma unroll 1
    for (int i2 = 0; i2 < M_DIM / 128; ++i2) {   // 16 iterations, 2 tiles each
        const int t0 = i2 * 128;
        __syncthreads();
        stage(1, t0 + 64);                        // always valid: t0+64 <= 1984
        tile(smem[0][0], smem[0][1]);
        __syncthreads();
        if (t0 + 128 < M_DIM) stage(0, t0 + 128);
        tile(smem[1][0], smem[1][1]);
    }

    // ---- epilogue: both halves (R14-identical) ----
    const int aa = plane_i >> 4;
    const int hh = plane_i & 15;
#pragma unroll
    for (int qh = 0; qh < 2; qh++) {
        float lown = qh ? l1 : l0;
        const float lt = lown + __shfl_xor(lown, 32);
        const float inv = 1.f / lt;
        float* obase = out + ((size_t)(aa * M_DIM + q0 + qh * 32 + l31)) * E_DIM + hh * C_DIM;
#pragma unroll
        for (int db = 0; db < 2; db++) {
            const f32x16& ov = qh ? (db ? o11 : o10) : (db ? o01 : o00);
#pragma unroll
            for (int g4 = 0; g4 < 4; g4++) {
                float4v w;
#pragma unroll
                for (int j = 0; j < 4; j++) w[j] = ov[4 * g4 + j] * inv;
                int d0 = db * 32 + 8 * g4 + 4 * hi;
                *reinterpret_cast<float4v*>(obase + d0) = w;
            }
        }
    }
}

extern "C" void kernel_launch(void* const* d_in, const int* in_sizes, int n_in,
                              void* d_out, int out_size, void* d_ws, size_t ws_size,
                              hipStream_t stream)
{
    const float* q  = (const float*)d_in[0];
    const float* k  = (const float*)d_in[1];
    const float* v  = (const float*)d_in[2];
    const float* Wq = (const float*)d_in[3];
    const float* bq = (const float*)d_in[4];
    const float* Wk = (const float*)d_in[5];
    const float* bk = (const float*)d_in[6];
    const float* Wv = (const float*)d_in[7];
    const float* bv = (const float*)d_in[8];
    float* out = (float*)d_out;

    _Float16* qp = (_Float16*)d_ws;
    _Float16* kp = qp + PROJ_ELEMS;
    _Float16* vt = kp + PROJ_ELEMS;

    const size_t e2 = (size_t)E_DIM * E_DIM;
    const size_t need_bytes = ((size_t)PROJ_ELEMS * 3 + 3 * e2) * sizeof(_Float16);
    _Float16* wh = (ws_size >= need_bytes) ? (vt + PROJ_ELEMS) : (_Float16*)d_out;

    hipLaunchKernelGGL(wcvt_kernel, dim3(512, 3), dim3(256), 0, stream, Wq, Wk, Wv, wh);

    dim3 pg(64, 8), pb(256);
    hipLaunchKernelGGL((proj_kernel<0>), pg, pb, 0, stream, q, wh,          bq, qp);
    hipLaunchKernelGGL((proj_kernel<0>), pg, pb, 0, stream, k, wh + e2,     bk, kp);
    hipLaunchKernelGGL((proj_kernel<1>), pg, pb, 0, stream, v, wh + 2 * e2, bv, vt);
    hipLaunchKernelGGL(flash_kernel, dim3(A_DIM * H_DIM * (M_DIM / 256)), dim3(256), 0, stream, qp, kp, vt, out);
}

// Round 16
// 177.839 us; speedup vs baseline: 1.0522x; 1.0522x over previous
//
#include <hip/hip_runtime.h>
#include <hip/hip_bf16.h>
#include <hip/hip_fp16.h>

using half8  = __attribute__((ext_vector_type(8))) _Float16;
using float4v = __attribute__((ext_vector_type(4))) float;
using f32x16 = __attribute__((ext_vector_type(16))) float;
typedef unsigned int uint;

#define A_DIM 4
#define M_DIM 2048
#define E_DIM 1024
#define H_DIM 16
#define C_DIM 64
#define PLANE (M_DIM * C_DIM)              // 131072 elements per (a,h)
#define PROJ_ELEMS (A_DIM * H_DIM * PLANE) // 8388608
#define LOG2E 1.44269504088896f

#define GLOAD_LDS16(g, l) __builtin_amdgcn_global_load_lds( \
    (const __attribute__((address_space(1))) void*)(g), \
    (__attribute__((address_space(3))) void*)(l), 16, 0, 0)

#if __has_builtin(__builtin_amdgcn_exp2f)
#define EXP2F(x) __builtin_amdgcn_exp2f(x)
#else
#define EXP2F(x) exp2f(x)
#endif

// f32 pair -> packed fp16 (RTZ) as uint bits
static __device__ __forceinline__ uint pk16(float a, float b) {
    auto r = __builtin_amdgcn_cvt_pkrtz(a, b);   // __fp16 x2
    return __builtin_bit_cast(uint, r);
}

// read 8 logical-contiguous f32 from a swizzled f32 LDS tile (256B rows,
// 16B blocks XOR'd by (row&7)<<4), convert to half8 via cvt_pkrtz. [R6-exact]
static __device__ __forceinline__ half8 ldsfrag_cvt256(const float* base, int row, int colbyte) {
    const char* b = (const char*)base;
    int off = row * 256 + (colbyte ^ ((row & 7) << 4));
    float4v x0 = *reinterpret_cast<const float4v*>(b + off);
    float4v x1 = *reinterpret_cast<const float4v*>(b + (off ^ 16));
    union { uint u[4]; half8 v; } r;
    r.u[0] = pk16(x0[0], x0[1]);
    r.u[1] = pk16(x0[2], x0[3]);
    r.u[2] = pk16(x1[0], x1[1]);
    r.u[3] = pk16(x1[2], x1[3]);
    return r.v;
}

// ---------------------------------------------------------------------------
// W f32 -> fp16 prepass (FROZEN from R12).
// ---------------------------------------------------------------------------
__global__ __launch_bounds__(256)
void wcvt_kernel(const float* __restrict__ Wq, const float* __restrict__ Wk,
                 const float* __restrict__ Wv, _Float16* __restrict__ wh)
{
    const float* W = (blockIdx.y == 0) ? Wq : (blockIdx.y == 1) ? Wk : Wv;
    _Float16* o = wh + (size_t)blockIdx.y * E_DIM * E_DIM;
    int i = (blockIdx.x * 256 + threadIdx.x) * 8;
    float4v x0 = *reinterpret_cast<const float4v*>(&W[i]);
    float4v x1 = *reinterpret_cast<const float4v*>(&W[i + 4]);
    union { uint u[4]; half8 h; } r;
    r.u[0] = pk16(x0[0], x0[1]);
    r.u[1] = pk16(x0[2], x0[3]);
    r.u[2] = pk16(x1[0], x1[1]);
    r.u[3] = pk16(x1[2], x1[3]);
    *reinterpret_cast<half8*>(&o[i]) = r.h;
}

// ---------------------------------------------------------------------------
// Projection GEMM, MERGED: grid (64, 8, 3); z selects (X, W, b, out).
// Body byte-equivalent to R12's proven kernel (runtime TR instead of
// template MODE). Removes 2 launch gaps; k/v-proj blocks fill CUs during
// q-proj tail. A staged f32 via global_load_lds + cvt at read; B staged
// fp16 (prepass). LDS 48KB -> 3 blocks/CU.
// ---------------------------------------------------------------------------
__global__ __launch_bounds__(256, 3)
void proj_kernel(const float* __restrict__ q, const float* __restrict__ k,
                 const float* __restrict__ v, const _Float16* __restrict__ wh,
                 const float* __restrict__ bq, const float* __restrict__ bk,
                 const float* __restrict__ bv,
                 _Float16* __restrict__ qp, _Float16* __restrict__ kp,
                 _Float16* __restrict__ vt)
{
    __shared__ float    ldsA[128 * 64];   // 32 KB, 256B rows (f32)
    __shared__ _Float16 ldsB[128 * 64];   // 16 KB, 128B rows (fp16)

    const int z = blockIdx.z;
    const float* X     = (z == 0) ? q  : (z == 1) ? k  : v;
    const _Float16* Wh = wh + (size_t)z * E_DIM * E_DIM;
    const float* bias  = (z == 0) ? bq : (z == 1) ? bk : bv;
    _Float16* out      = (z == 0) ? qp : (z == 1) ? kp : vt;
    const bool TR = (z == 2);

    const int tid  = threadIdx.x;
    const int lane = tid & 63;
    const int wave = tid >> 6;
    const int wr = wave >> 1, wc = wave & 1;
    const int g = lane >> 4, r16 = lane & 15;
    const int R0 = blockIdx.x * 128;
    const int C0 = blockIdx.y * 128;

    float4v acc[4][4];
#pragma unroll
    for (int i = 0; i < 4; i++)
#pragma unroll
        for (int j = 0; j < 4; j++) acc[i][j] = {0.f, 0.f, 0.f, 0.f};

    for (int k0 = 0; k0 < E_DIM; k0 += 64) {
        __syncthreads();
#pragma unroll
        for (int i = 0; i < 8; i++) {          // A: 2048 16B-segs, f32
            int s    = i * 256 + tid;
            int row  = s >> 4;
            int swzo = ((s & 15) * 16) ^ ((row & 7) << 4);
            const char* asrc = (const char*)&X[(size_t)(R0 + row) * E_DIM + k0] + swzo;
            GLOAD_LDS16(asrc, &ldsA[s * 4]);
        }
#pragma unroll
        for (int i = 0; i < 4; i++) {          // B: 1024 16B-segs, fp16
            int s    = i * 256 + tid;
            int row  = s >> 3;
            int swzo = ((s & 7) * 16) ^ ((row & 7) << 4);
            const char* bsrc = (const char*)&Wh[(size_t)(C0 + row) * E_DIM + k0] + swzo;
            GLOAD_LDS16(bsrc, &ldsB[s * 8]);
        }
        __syncthreads();

#pragma unroll
        for (int kc = 0; kc < 2; kc++) {
            half8 af[4], bf[4];
#pragma unroll
            for (int mi = 0; mi < 4; mi++)
                af[mi] = ldsfrag_cvt256(ldsA, wr * 64 + mi * 16 + r16, kc * 128 + g * 32);
#pragma unroll
            for (int ni = 0; ni < 4; ni++) {
                int row = wc * 64 + ni * 16 + r16;
                bf[ni] = *reinterpret_cast<const half8*>(
                    (const char*)ldsB + row * 128 + ((kc * 64 + g * 16) ^ ((row & 7) << 4)));
            }
#pragma unroll
            for (int mi = 0; mi < 4; mi++)
#pragma unroll
                for (int ni = 0; ni < 4; ni++)
                    acc[mi][ni] = __builtin_amdgcn_mfma_f32_16x16x32_f16(af[mi], bf[ni], acc[mi][ni], 0, 0, 0);
        }
    }

#pragma unroll
    for (int mi = 0; mi < 4; mi++) {
#pragma unroll
        for (int ni = 0; ni < 4; ni++) {
            const int jb = C0 + wc * 64 + ni * 16 + r16;
            const int h  = jb >> 6;
            const int cc = jb & 63;
            const float bv = bias[jb];
            if (!TR) {
#pragma unroll
                for (int reg = 0; reg < 4; reg++) {
                    int b = R0 + wr * 64 + mi * 16 + g * 4 + reg;
                    float val = acc[mi][ni][reg] + bv;
                    size_t o = (size_t)((b >> 11) * H_DIM + h) * PLANE + (size_t)(b & (M_DIM - 1)) * C_DIM + cc;
                    out[o] = (_Float16)val;
                }
            } else {
                int b0 = R0 + wr * 64 + mi * 16 + g * 4;
                uint u0 = pk16(acc[mi][ni][0] + bv, acc[mi][ni][1] + bv);
                uint u1 = pk16(acc[mi][ni][2] + bv, acc[mi][ni][3] + bv);
                size_t o = (size_t)((b0 >> 11) * H_DIM + h) * PLANE + (size_t)cc * M_DIM + (b0 & (M_DIM - 1));
                *reinterpret_cast<uint*>(&out[o]) = u0;
                *reinterpret_cast<uint*>(&out[o] + 2) = u1;
            }
        }
    }
}

// ---------------------------------------------------------------------------
// Flash attention (REVERTED to R14-exact, best measured: 102.2 us):
// 64 q-rows per wave, shared kf/vf reads, 512 blocks, R13-verified softmax
// (unconditional exp + rare fixup) and permlane32_swap pack.
// ---------------------------------------------------------------------------
__global__ __launch_bounds__(256, 2)
void flash_kernel(const _Float16* __restrict__ qp, const _Float16* __restrict__ kp,
                  const _Float16* __restrict__ vt, float* __restrict__ out)
{
    __shared__ _Float16 smem[2][2][4096];   // [dbuf][K|V][64 rows x 64 cols]

    const int tid  = threadIdx.x;
    const int lane = tid & 63;
    const int wave = tid >> 6;
    const int l31  = lane & 31;
    const int hi   = lane >> 5;

    // 512 wgs, 8 XCDs -> each XCD owns 8 whole planes (K/V fit its L2)
    const int bid = blockIdx.x;
    const int wg  = ((bid & 7) << 6) | (bid >> 3);
    const int plane_i = wg >> 3;          // 0..63
    const int qt      = wg & 7;           // 0..7 : 256-q-row block
    const size_t plane = (size_t)plane_i * PLANE;
    const int q0 = qt * 256 + wave * 64;  // wave's two halves: q0, q0+32

    const int srow  = tid >> 3;
    const int lincb = (tid & 7) * 16;
    const int scb   = lincb ^ ((srow & 7) << 4);

    half8 qf0[4], qf1[4];
#pragma unroll
    for (int ch = 0; ch < 4; ch++) {
        qf0[ch] = *reinterpret_cast<const half8*>(&qp[plane + (size_t)(q0 + l31) * C_DIM + ch * 16 + hi * 8]);
        qf1[ch] = *reinterpret_cast<const half8*>(&qp[plane + (size_t)(q0 + 32 + l31) * C_DIM + ch * 16 + hi * 8]);
    }

    f32x16 o00, o01, o10, o11;            // [qh][db]
#pragma unroll
    for (int i = 0; i < 16; i++) { o00[i] = 0.f; o01[i] = 0.f; o10[i] = 0.f; o11[i] = 0.f; }
    float m0 = 0.f, mK0 = 0.f, l0 = 0.f;
    float m1 = 0.f, mK1 = 0.f, l1 = 0.f;

    auto stage = [&](int buf, int t0) {
#pragma unroll
        for (int i = 0; i < 2; i++) {
            int row = srow + 32 * i;
            const char* ksrc = (const char*)&kp[plane + (size_t)(t0 + row) * C_DIM] + scb;
            const char* vsrc = (const char*)&vt[plane + (size_t)row * M_DIM + t0] + scb;
            GLOAD_LDS16(ksrc, &smem[buf][0][tid * 8 + 2048 * i]);
            GLOAD_LDS16(vsrc, &smem[buf][1][tid * 8 + 2048 * i]);
        }
    };

    stage(0, 0);

    for (int it = 0; it < M_DIM / 64; ++it) {
        __syncthreads();
        if (it + 1 < M_DIM / 64) stage((it + 1) & 1, (it + 1) * 64);
        const int cur = it & 1;
        const char* kbase = (const char*)smem[cur][0];
        const char* vbase = (const char*)smem[cur][1];

#pragma unroll
        for (int st = 0; st < 2; ++st) {
            const int krow = st * 32 + l31;
            const int kswz = (krow & 7) << 4;

            half8 kf[4];
#pragma unroll
            for (int ch = 0; ch < 4; ch++)
                kf[ch] = *reinterpret_cast<const half8*>(kbase + krow * 128 + ((ch * 32 + hi * 16) ^ kswz));

            f32x16 s0, s1;
#pragma unroll
            for (int i = 0; i < 16; i++) { s0[i] = 0.f; s1[i] = 0.f; }
            __builtin_amdgcn_s_setprio(1);
#pragma unroll
            for (int ch = 0; ch < 4; ch++) {
                s0 = __builtin_amdgcn_mfma_f32_32x32x16_f16(kf[ch], qf0[ch], s0, 0, 0, 0);
                s1 = __builtin_amdgcn_mfma_f32_32x32x16_f16(kf[ch], qf1[ch], s1, 0, 0, 0);
            }
            __builtin_amdgcn_s_setprio(0);

            half8 pf0[2], pf1[2];
#pragma unroll
            for (int qh = 0; qh < 2; qh++) {
                f32x16& s = qh ? s1 : s0;
                float& m = qh ? m1 : m0;
                float& mK = qh ? mK1 : mK0;
                float& l = qh ? l1 : l0;
                half8* pf = qh ? pf1 : pf0;
                f32x16& oa = qh ? o10 : o00;
                f32x16& ob = qh ? o11 : o01;

                float p[16];
#pragma unroll
                for (int r = 0; r < 16; r++) p[r] = EXP2F(fmaf(s[r], LOG2E, -mK));

                float a0 = fmaxf(fmaxf(s[0],  s[1]),  s[2]);
                float a1 = fmaxf(fmaxf(s[3],  s[4]),  s[5]);
                float a2 = fmaxf(fmaxf(s[6],  s[7]),  s[8]);
                float a3 = fmaxf(fmaxf(s[9],  s[10]), s[11]);
                float a4 = fmaxf(fmaxf(s[12], s[13]), s[14]);
                float pm = fmaxf(fmaxf(fmaxf(a0, a1), a2),
                                 fmaxf(fmaxf(a3, a4), s[15]));
                pm = fmaxf(pm, __shfl_xor(pm, 32));
                if (!__all(pm <= m + 8.f)) {
                    float mnew = fmaxf(m, pm);
                    float sc = EXP2F((m - mnew) * LOG2E);
                    m = mnew; mK = m * LOG2E;
                    l *= sc;
                    oa *= sc; ob *= sc;
#pragma unroll
                    for (int r = 0; r < 16; r++) p[r] *= sc;
                }
                float t0a = (p[0] + p[1]) + (p[2] + p[3]);
                float t1a = (p[4] + p[5]) + (p[6] + p[7]);
                float t2a = (p[8] + p[9]) + (p[10] + p[11]);
                float t3a = (p[12] + p[13]) + (p[14] + p[15]);
                l += (t0a + t1a) + (t2a + t3a);

#pragma unroll
                for (int c0 = 0; c0 < 2; c0++) {
                    uint ua0 = pk16(p[8 * c0 + 0], p[8 * c0 + 1]);
                    uint ua1 = pk16(p[8 * c0 + 2], p[8 * c0 + 3]);
                    uint ub0 = pk16(p[8 * c0 + 4], p[8 * c0 + 5]);
                    uint ub1 = pk16(p[8 * c0 + 6], p[8 * c0 + 7]);
                    union { int u[4]; half8 v; } pu;
#if __has_builtin(__builtin_amdgcn_permlane32_swap)
                    auto r0 = __builtin_amdgcn_permlane32_swap((int)ua0, (int)ub0, false, false);
                    auto r1 = __builtin_amdgcn_permlane32_swap((int)ua1, (int)ub1, false, false);
                    pu.u[0] = r0[0];
                    pu.u[1] = r1[0];
                    pu.u[2] = r0[1];
                    pu.u[3] = r1[1];
#else
                    uint v0 = hi ? ua0 : ub0;
                    uint v1 = hi ? ua1 : ub1;
                    uint y0 = (uint)__shfl_xor((int)v0, 32);
                    uint y1 = (uint)__shfl_xor((int)v1, 32);
                    pu.u[0] = hi ? y0 : ua0;
                    pu.u[1] = hi ? y1 : ua1;
                    pu.u[2] = hi ? ub0 : y0;
                    pu.u[3] = hi ? ub1 : y1;
#endif
                    pf[c0] = pu.v;
                }
            }

            __builtin_amdgcn_s_setprio(1);
#pragma unroll
            for (int db = 0; db < 2; db++) {
                const int vrow = db * 32 + l31;
                const int vswz = (vrow & 7) << 4;
#pragma unroll
                for (int c0 = 0; c0 < 2; c0++) {
                    half8 vf = *reinterpret_cast<const half8*>(
                        vbase + vrow * 128 + ((st * 64 + c0 * 32 + hi * 16) ^ vswz));
                    if (db == 0) {
                        o00 = __builtin_amdgcn_mfma_f32_32x32x16_f16(vf, pf0[c0], o00, 0, 0, 0);
                        o10 = __builtin_amdgcn_mfma_f32_32x32x16_f16(vf, pf1[c0], o10, 0, 0, 0);
                    } else {
                        o01 = __builtin_amdgcn_mfma_f32_32x32x16_f16(vf, pf0[c0], o01, 0, 0, 0);
                        o11 = __builtin_amdgcn_mfma_f32_32x32x16_f16(vf, pf1[c0], o11, 0, 0, 0);
                    }
                }
            }
            __builtin_amdgcn_s_setprio(0);
        }
    }

    const int aa = plane_i >> 4;
    const int hh = plane_i & 15;
#pragma unroll
    for (int qh = 0; qh < 2; qh++) {
        float lown = qh ? l1 : l0;
        const float lt = lown + __shfl_xor(lown, 32);
        const float inv = 1.f / lt;
        float* obase = out + ((size_t)(aa * M_DIM + q0 + qh * 32 + l31)) * E_DIM + hh * C_DIM;
#pragma unroll
        for (int db = 0; db < 2; db++) {
            const f32x16& ov = qh ? (db ? o11 : o10) : (db ? o01 : o00);
#pragma unroll
            for (int g4 = 0; g4 < 4; g4++) {
                float4v w;
#pragma unroll
                for (int j = 0; j < 4; j++) w[j] = ov[4 * g4 + j] * inv;
                int d0 = db * 32 + 8 * g4 + 4 * hi;
                *reinterpret_cast<float4v*>(obase + d0) = w;
            }
        }
    }
}

extern "C" void kernel_launch(void* const* d_in, const int* in_sizes, int n_in,
                              void* d_out, int out_size, void* d_ws, size_t ws_size,
                              hipStream_t stream)
{
    const float* q  = (const float*)d_in[0];
    const float* k  = (const float*)d_in[1];
    const float* v  = (const float*)d_in[2];
    const float* Wq = (const float*)d_in[3];
    const float* bq = (const float*)d_in[4];
    const float* Wk = (const float*)d_in[5];
    const float* bk = (const float*)d_in[6];
    const float* Wv = (const float*)d_in[7];
    const float* bv = (const float*)d_in[8];
    float* out = (float*)d_out;

    _Float16* qp = (_Float16*)d_ws;
    _Float16* kp = qp + PROJ_ELEMS;
    _Float16* vt = kp + PROJ_ELEMS;

    const size_t e2 = (size_t)E_DIM * E_DIM;
    const size_t need_bytes = ((size_t)PROJ_ELEMS * 3 + 3 * e2) * sizeof(_Float16);
    _Float16* wh = (ws_size >= need_bytes) ? (vt + PROJ_ELEMS) : (_Float16*)d_out;

    hipLaunchKernelGGL(wcvt_kernel, dim3(512, 3), dim3(256), 0, stream, Wq, Wk, Wv, wh);
    hipLaunchKernelGGL(proj_kernel, dim3(64, 8, 3), dim3(256), 0, stream,
                       q, k, v, wh, bq, bk, bv, qp, kp, vt);
    hipLaunchKernelGGL(flash_kernel, dim3(A_DIM * H_DIM * (M_DIM / 256)), dim3(256), 0, stream, qp, kp, vt, out);
}